// Round 1
// baseline (1489.691 us; speedup 1.0000x reference)
//
#include <hip/hip_runtime.h>

#define HW 784
#define WD 28

// ---------------------------------------------------------------------------
// Prep: fold BN into transposed weight layouts.
// wdownT[c][cr] = w_down[cr][c]*s1[cr];             bias1[cr]
// wtT[cc][tap][o] = tconv_w[o][c][dt][ky][kx]  (cc=dt*64+c, tap=ky*3+kx)
// AtBt[o] = s/8 ; AtBt[64+o] = (tb-m)*s+b
// off3T[c][tap][oc], off5T[c][tap][oc]   (raw, bias applied at use)
// def3T[k][c][o], def5T[k][c][o]
// c1T[c][o] = conv1_w[o][c]*s3[o];  B3[o]
// gwT[c][co] = conv_w[co][c]*s2[co]; Bg[co]
// ---------------------------------------------------------------------------
__global__ void k_prep(
    const float* __restrict__ w_down, const float* __restrict__ b_down,
    const float* __restrict__ bn1_g, const float* __restrict__ bn1_b,
    const float* __restrict__ bn1_m, const float* __restrict__ bn1_v,
    const float* __restrict__ tconv_w, const float* __restrict__ tconv_b,
    const float* __restrict__ bnt_g, const float* __restrict__ bnt_b,
    const float* __restrict__ bnt_m, const float* __restrict__ bnt_v,
    const float* __restrict__ off3_w, const float* __restrict__ def3_w,
    const float* __restrict__ off5_w, const float* __restrict__ def5_w,
    const float* __restrict__ conv1_w, const float* __restrict__ conv1_b,
    const float* __restrict__ bn3_g, const float* __restrict__ bn3_b,
    const float* __restrict__ bn3_m, const float* __restrict__ bn3_v,
    const float* __restrict__ conv_w, const float* __restrict__ conv_b,
    const float* __restrict__ bn2_g, const float* __restrict__ bn2_b,
    const float* __restrict__ bn2_m, const float* __restrict__ bn2_v,
    float* __restrict__ wdownT, float* __restrict__ bias1,
    float* __restrict__ wtT, float* __restrict__ AtBt,
    float* __restrict__ off3T, float* __restrict__ off5T,
    float* __restrict__ def3T, float* __restrict__ def5T,
    float* __restrict__ c1T, float* __restrict__ B3,
    float* __restrict__ gwT, float* __restrict__ Bg)
{
  const int tid = blockIdx.x * blockDim.x + threadIdx.x;
  const int nth = gridDim.x * blockDim.x;
  for (int i = tid; i < 256 * 64; i += nth) {
    int c = i >> 6, cr = i & 63;
    float s = bn1_g[cr] / sqrtf(bn1_v[cr] + 1e-5f);
    wdownT[i] = w_down[cr * 256 + c] * s;
  }
  for (int i = tid; i < 64; i += nth) {
    float s = bn1_g[i] / sqrtf(bn1_v[i] + 1e-5f);
    bias1[i] = (b_down[i] - bn1_m[i]) * s + bn1_b[i];
  }
  for (int i = tid; i < 192 * 9 * 64; i += nth) {
    int cc = i / (9 * 64); int tap = (i / 64) % 9; int o = i & 63;
    int dt = cc >> 6, c = cc & 63;
    wtT[i] = tconv_w[o * 1728 + c * 27 + dt * 9 + tap];
  }
  for (int i = tid; i < 64; i += nth) {
    float s = bnt_g[i] / sqrtf(bnt_v[i] + 1e-5f);
    AtBt[i] = s * 0.125f;
    AtBt[64 + i] = (tconv_b[i] - bnt_m[i]) * s + bnt_b[i];
  }
  for (int i = tid; i < 64 * 9 * 18; i += nth) {
    int c = i / (9 * 18); int tap = (i / 18) % 9; int oc = i % 18;
    off3T[i] = off3_w[oc * 576 + c * 9 + tap];
  }
  for (int i = tid; i < 64 * 25 * 50; i += nth) {
    int c = i / 1250; int tap = (i / 50) % 25; int oc = i % 50;
    off5T[i] = off5_w[oc * 1600 + c * 25 + tap];
  }
  for (int i = tid; i < 9 * 64 * 64; i += nth) {
    int k = i >> 12; int c = (i >> 6) & 63; int o = i & 63;
    def3T[i] = def3_w[o * 576 + c * 9 + k];
  }
  for (int i = tid; i < 25 * 64 * 64; i += nth) {
    int k = i >> 12; int c = (i >> 6) & 63; int o = i & 63;
    def5T[i] = def5_w[o * 1600 + c * 25 + k];
  }
  for (int i = tid; i < 64 * 64; i += nth) {
    int c = i >> 6, o = i & 63;
    float s = bn3_g[o] / sqrtf(bn3_v[o] + 1e-5f);
    c1T[i] = conv1_w[o * 64 + c] * s;
  }
  for (int i = tid; i < 64; i += nth) {
    float s = bn3_g[i] / sqrtf(bn3_v[i] + 1e-5f);
    B3[i] = (conv1_b[i] - bn3_m[i]) * s + bn3_b[i];
  }
  for (int i = tid; i < 64 * 256; i += nth) {
    int c = i >> 8, co = i & 255;
    float s = bn2_g[co] / sqrtf(bn2_v[co] + 1e-5f);
    gwT[i] = conv_w[co * 64 + c] * s;
  }
  for (int i = tid; i < 256; i += nth) {
    float s = bn2_g[i] / sqrtf(bn2_v[i] + 1e-5f);
    Bg[i] = (conv_b[i] - bn2_m[i]) * s + bn2_b[i];
  }
}

// ---------------------------------------------------------------------------
// 1x1 down conv (256->64) + folded BN.  64 accumulators/thread, W in LDS
// (wave-uniform broadcast reads -> conflict-free).
// ---------------------------------------------------------------------------
__global__ __launch_bounds__(256) void k_down(
    const float* __restrict__ x, const float* __restrict__ wdownT,
    const float* __restrict__ bias1, float* __restrict__ out)
{
  __shared__ float wl[256 * 64];            // 64 KB
  const int tid = threadIdx.x;
  {
    const float4* s4 = (const float4*)wdownT;
    float4* d4 = (float4*)wl;
    for (int i = tid; i < 256 * 16; i += 256) d4[i] = s4[i];
  }
  __syncthreads();
  const int f = blockIdx.x;
  const int px = blockIdx.y * 256 + tid;
  const bool act = px < HW;
  const int pxe = act ? px : 0;
  const float* xp = x + (size_t)f * 256 * HW + pxe;
  float acc[64];
#pragma unroll
  for (int j = 0; j < 64; j++) acc[j] = 0.f;
#pragma unroll 4
  for (int c = 0; c < 256; c++) {
    float xv = xp[c * HW];
    const float* wr = &wl[c * 64];
#pragma unroll
    for (int j = 0; j < 64; j++) acc[j] += xv * wr[j];
  }
  if (act) {
    float* op = out + (size_t)f * 64 * HW + px;
#pragma unroll
    for (int j = 0; j < 64; j++) op[j * HW] = acc[j] + bias1[j];
  }
}

// ---------------------------------------------------------------------------
// Build U planes for the collapsed temporal conv:
// U[b][0*64+c]=S-out[t=7], U[b][64+c]=S, U[b][128+c]=S-out[t=0]
// ---------------------------------------------------------------------------
__global__ void k_makeU(const float* __restrict__ out, float* __restrict__ U)
{
  const int idx = blockIdx.x * 256 + threadIdx.x;   // < 8*64*784
  const int b = idx / (64 * HW);
  const int r = idx % (64 * HW);
  const float* p = out + (size_t)b * 8 * 64 * HW + r;
  float v0 = p[0];
  float s = v0, v = v0;
#pragma unroll
  for (int t = 1; t < 8; t++) { v = p[t * 64 * HW]; s += v; }
  float* u = U + (size_t)b * 192 * HW + r;
  u[0] = s - v;          // dt=0 pairs with in[t+1] missing at end
  u[64 * HW] = s;        // dt=1
  u[128 * HW] = s - v0;  // dt=2
}

// ---------------------------------------------------------------------------
// Collapsed temporal conv: 3x3 conv, 192->64, + (1/T) + BN fold.
// Grid (b=8, 4 px tiles, 8 o-groups of 8).
// ---------------------------------------------------------------------------
__global__ __launch_bounds__(256) void k_tconv(
    const float* __restrict__ U, const float* __restrict__ wtT,
    const float* __restrict__ AtBt, float* __restrict__ t_out)
{
  __shared__ float wl[16 * 9 * 8];
  const int tid = threadIdx.x;
  const int b = blockIdx.x;
  const int px = blockIdx.y * 256 + tid;
  const int o0 = blockIdx.z * 8;
  const bool act = px < HW;
  const int pxe = act ? px : 0;
  const int y = pxe / WD, x = pxe % WD;
  int lin[9]; float msk[9];
#pragma unroll
  for (int t = 0; t < 9; t++) {
    int iy = y + t / 3 - 1, ix = x + t % 3 - 1;
    bool ok = iy >= 0 && iy < WD && ix >= 0 && ix < WD;
    lin[t] = min(max(iy, 0), WD - 1) * WD + min(max(ix, 0), WD - 1);
    msk[t] = ok ? 1.f : 0.f;
  }
  float acc[8];
#pragma unroll
  for (int j = 0; j < 8; j++) acc[j] = 0.f;
  const float* ub = U + (size_t)b * 192 * HW;
  for (int ccb = 0; ccb < 12; ccb++) {
    __syncthreads();
    for (int i = tid; i < 1152; i += 256) {
      int ccL = i / 72; int rr = i % 72; int tap = rr >> 3; int j = rr & 7;
      wl[i] = wtT[((ccb * 16 + ccL) * 9 + tap) * 64 + o0 + j];
    }
    __syncthreads();
    for (int ccL = 0; ccL < 16; ccL++) {
      const float* p = ub + (ccb * 16 + ccL) * HW;
      float v[9];
#pragma unroll
      for (int t = 0; t < 9; t++) v[t] = p[lin[t]] * msk[t];
      const float* wr = &wl[ccL * 72];
#pragma unroll
      for (int t = 0; t < 9; t++)
#pragma unroll
        for (int j = 0; j < 8; j++) acc[j] += v[t] * wr[t * 8 + j];
    }
  }
  if (act) {
#pragma unroll
    for (int j = 0; j < 8; j++) {
      int o = o0 + j;
      t_out[(size_t)(b * 64 + o) * HW + px] = acc[j] * AtBt[o] + AtBt[64 + o];
    }
  }
}

// ---------------------------------------------------------------------------
// Offset convs: direct KSxKS conv 64->OC on x_post frames.
// ---------------------------------------------------------------------------
template <int KS, int PAD, int OC, int CCH>
__global__ __launch_bounds__(256) void k_offconv(
    const float* __restrict__ frames, const float* __restrict__ wT,
    const float* __restrict__ bias, float* __restrict__ dst)
{
  constexpr int K2 = KS * KS;
  __shared__ float wl[CCH * K2 * OC];
  const int tid = threadIdx.x;
  const int n = blockIdx.x;
  const int f = (n / 7) * 8 + (n % 7) + 1;
  const int px = blockIdx.y * 256 + tid;
  const bool act = px < HW;
  const int pxe = act ? px : 0;
  const int y = pxe / WD, x = pxe % WD;
  int lin[K2]; float msk[K2];
#pragma unroll
  for (int t = 0; t < K2; t++) {
    int iy = y + t / KS - PAD, ix = x + t % KS - PAD;
    bool ok = iy >= 0 && iy < WD && ix >= 0 && ix < WD;
    lin[t] = min(max(iy, 0), WD - 1) * WD + min(max(ix, 0), WD - 1);
    msk[t] = ok ? 1.f : 0.f;
  }
  float acc[OC];
#pragma unroll
  for (int j = 0; j < OC; j++) acc[j] = 0.f;
  const float* sb = frames + (size_t)f * 64 * HW;
  for (int cb = 0; cb < 64 / CCH; cb++) {
    __syncthreads();
    for (int i = tid; i < CCH * K2 * OC; i += 256)
      wl[i] = wT[cb * (CCH * K2 * OC) + i];
    __syncthreads();
    for (int cL = 0; cL < CCH; cL++) {
      const float* p = sb + (cb * CCH + cL) * HW;
      float v[K2];
#pragma unroll
      for (int t = 0; t < K2; t++) v[t] = p[lin[t]] * msk[t];
      const float* wr = &wl[cL * K2 * OC];
#pragma unroll
      for (int t = 0; t < K2; t++)
#pragma unroll
        for (int j = 0; j < OC; j++) acc[j] += v[t] * wr[t * OC + j];
    }
  }
  if (act) {
#pragma unroll
    for (int j = 0; j < OC; j++)
      dst[(size_t)(n * OC + j) * HW + px] = acc[j] + bias[j];
  }
}

// ---------------------------------------------------------------------------
// Deformable conv: thread=pixel, 64 o-accumulators, bilinear gather per (k,c)
// with validity folded into corner weights; per-k weight slice staged in LDS.
// ---------------------------------------------------------------------------
template <int KS, int PAD, bool ACCUM>
__global__ __launch_bounds__(256) void k_deform(
    const float* __restrict__ frames, const float* __restrict__ offs,
    const float* __restrict__ wT, float* __restrict__ dst)
{
  constexpr int K2 = KS * KS;
  __shared__ float wl[64 * 64];             // 16 KB
  const int tid = threadIdx.x;
  const int n = blockIdx.x;
  const int f = (n / 7) * 8 + (n % 7) + 1;
  const int px = blockIdx.y * 256 + tid;
  const bool act = px < HW;
  const int pxe = act ? px : 0;
  const int y = pxe / WD, x = pxe % WD;
  const float* sb = frames + (size_t)f * 64 * HW;
  const float* ob = offs + (size_t)n * (2 * K2) * HW + pxe;
  float acc[64];
#pragma unroll
  for (int j = 0; j < 64; j++) acc[j] = 0.f;
  for (int k = 0; k < K2; k++) {
    __syncthreads();
    {
      const float4* s4 = (const float4*)(wT + k * 4096);
      float4* d4 = (float4*)wl;
      for (int i = tid; i < 1024; i += 256) d4[i] = s4[i];
    }
    __syncthreads();
    float offy = ob[(2 * k) * HW];
    float offx = ob[(2 * k + 1) * HW];
    float py = (float)(y + k / KS - PAD) + offy;
    float pxx = (float)(x + k % KS - PAD) + offx;
    float fy = floorf(py), fx = floorf(pxx);
    int y0 = (int)fy, x0 = (int)fx;
    float ly = py - fy, lx = pxx - fx;
    int y1 = y0 + 1, x1 = x0 + 1;
    float vy0 = (y0 >= 0 && y0 < WD) ? 1.f : 0.f;
    float vy1 = (y1 >= 0 && y1 < WD) ? 1.f : 0.f;
    float vx0 = (x0 >= 0 && x0 < WD) ? 1.f : 0.f;
    float vx1 = (x1 >= 0 && x1 < WD) ? 1.f : 0.f;
    float w00 = (1.f - ly) * (1.f - lx) * vy0 * vx0;
    float w01 = (1.f - ly) * lx * vy0 * vx1;
    float w10 = ly * (1.f - lx) * vy1 * vx0;
    float w11 = ly * lx * vy1 * vx1;
    int cy0 = min(max(y0, 0), WD - 1), cy1 = min(max(y1, 0), WD - 1);
    int cx0 = min(max(x0, 0), WD - 1), cx1 = min(max(x1, 0), WD - 1);
    int l00 = cy0 * WD + cx0, l01 = cy0 * WD + cx1;
    int l10 = cy1 * WD + cx0, l11 = cy1 * WD + cx1;
    // manual prefetch pipeline over c
    float n00 = sb[l00], n01 = sb[l01], n10 = sb[l10], n11 = sb[l11];
    for (int c = 0; c < 64; c++) {
      float g00 = n00, g01 = n01, g10 = n10, g11 = n11;
      if (c < 63) {
        const float* q = sb + (c + 1) * HW;
        n00 = q[l00]; n01 = q[l01]; n10 = q[l10]; n11 = q[l11];
      }
      float g = g00 * w00 + g01 * w01 + g10 * w10 + g11 * w11;
      const float* wr = &wl[c * 64];
#pragma unroll
      for (int j = 0; j < 64; j++) acc[j] += g * wr[j];
    }
  }
  if (act) {
    float* dp = dst + (size_t)n * 64 * HW + px;
#pragma unroll
    for (int j = 0; j < 64; j++) {
      if (ACCUM) dp[j * HW] += acc[j];
      else dp[j * HW] = acc[j];
    }
  }
}

// ---------------------------------------------------------------------------
// maxpool 3x3 + 1x1 conv (BN folded) + diff epilogue:
// dsum <- |dsum + d_avg - 3*x_pre|
// ---------------------------------------------------------------------------
__global__ __launch_bounds__(256) void k_davg_diff(
    const float* __restrict__ frames, const float* __restrict__ c1T,
    const float* __restrict__ B3, float* __restrict__ dsum)
{
  __shared__ float wl[64 * 64];
  const int tid = threadIdx.x;
  {
    const float4* s4 = (const float4*)c1T;
    float4* d4 = (float4*)wl;
    for (int i = tid; i < 1024; i += 256) d4[i] = s4[i];
  }
  __syncthreads();
  const int n = blockIdx.x;
  const int b = n / 7, t = n % 7;
  const int fpost = b * 8 + t + 1, fpre = b * 8 + t;
  const int px = blockIdx.y * 256 + tid;
  const bool act = px < HW;
  const int pxe = act ? px : 0;
  const int y = pxe / WD, x = pxe % WD;
  int lin[9]; bool okm[9];
#pragma unroll
  for (int t2 = 0; t2 < 9; t2++) {
    int iy = y + t2 / 3 - 1, ix = x + t2 % 3 - 1;
    okm[t2] = iy >= 0 && iy < WD && ix >= 0 && ix < WD;
    lin[t2] = min(max(iy, 0), WD - 1) * WD + min(max(ix, 0), WD - 1);
  }
  float acc[64];
#pragma unroll
  for (int j = 0; j < 64; j++) acc[j] = 0.f;
  const float* sb = frames + (size_t)fpost * 64 * HW;
  for (int c = 0; c < 64; c++) {
    const float* p = sb + c * HW;
    float m = -1e30f;
#pragma unroll
    for (int t2 = 0; t2 < 9; t2++) {
      float v = okm[t2] ? p[lin[t2]] : -1e30f;
      m = fmaxf(m, v);
    }
    const float* wr = &wl[c * 64];
#pragma unroll
    for (int j = 0; j < 64; j++) acc[j] += m * wr[j];
  }
  if (act) {
    const float* xpre = frames + (size_t)fpre * 64 * HW + px;
    float* dp = dsum + (size_t)n * 64 * HW + px;
#pragma unroll
    for (int j = 0; j < 64; j++) {
      float d = dp[j * HW] + (acc[j] + B3[j]) - 3.f * xpre[j * HW];
      dp[j * HW] = fabsf(d);
    }
  }
}

// ---------------------------------------------------------------------------
// Spatial mean of cat = [diff frames 0..6 | t_out] per (nt, c).
// ---------------------------------------------------------------------------
__global__ void k_gmean(const float* __restrict__ dsum,
                        const float* __restrict__ t_out,
                        float* __restrict__ gmean)
{
  const int nt = blockIdx.x, c = blockIdx.y;
  const int b = nt >> 3, tt = nt & 7;
  const float* p = (tt < 7) ? (dsum + (size_t)((b * 7 + tt) * 64 + c) * HW)
                            : (t_out + (size_t)(b * 64 + c) * HW);
  const int tid = threadIdx.x;
  float s = 0.f;
  for (int i = tid; i < HW; i += 64) s += p[i];
#pragma unroll
  for (int o = 32; o > 0; o >>= 1) s += __shfl_down(s, o, 64);
  if (tid == 0) gmean[nt * 64 + c] = s * (1.f / HW);
}

// ---------------------------------------------------------------------------
// Gate: 1x1 conv 64->256 (BN folded) + sigmoid; store mult = 1+gate.
// ---------------------------------------------------------------------------
__global__ __launch_bounds__(256) void k_gate(
    const float* __restrict__ gmean, const float* __restrict__ gwT,
    const float* __restrict__ Bg, float* __restrict__ mult)
{
  __shared__ float gm[64];
  const int nt = blockIdx.x, co = threadIdx.x;
  if (co < 64) gm[co] = gmean[nt * 64 + co];
  __syncthreads();
  float a = 0.f;
#pragma unroll 8
  for (int c = 0; c < 64; c++) a += gm[c] * gwT[c * 256 + co];
  float pre = a + Bg[co];
  mult[nt * 256 + co] = 0.5f + 1.f / (1.f + expf(-pre));
}

// ---------------------------------------------------------------------------
// out = x * mult[nt,co]   (float4; 784 divisible by 4 so no plane crossing)
// ---------------------------------------------------------------------------
__global__ void k_apply(const float* __restrict__ x,
                        const float* __restrict__ mult,
                        float* __restrict__ outp)
{
  const int i = blockIdx.x * 256 + threadIdx.x;  // float4 index, 3211264 total
  const int plane = i / 196;                      // nt*256 + co
  const float m = mult[plane];
  float4 v = ((const float4*)x)[i];
  v.x *= m; v.y *= m; v.z *= m; v.w *= m;
  ((float4*)outp)[i] = v;
}

// ---------------------------------------------------------------------------
extern "C" void kernel_launch(void* const* d_in, const int* in_sizes, int n_in,
                              void* d_out, int out_size, void* d_ws, size_t ws_size,
                              hipStream_t stream)
{
  const float* x       = (const float*)d_in[0];
  const float* w_down  = (const float*)d_in[1];
  const float* b_down  = (const float*)d_in[2];
  const float* bn1_g   = (const float*)d_in[3];
  const float* bn1_b   = (const float*)d_in[4];
  const float* bn1_m   = (const float*)d_in[5];
  const float* bn1_v   = (const float*)d_in[6];
  const float* tconv_w = (const float*)d_in[7];
  const float* tconv_b = (const float*)d_in[8];
  const float* bnt_g   = (const float*)d_in[9];
  const float* bnt_b   = (const float*)d_in[10];
  const float* bnt_m   = (const float*)d_in[11];
  const float* bnt_v   = (const float*)d_in[12];
  const float* off3_w  = (const float*)d_in[13];
  const float* off3_b  = (const float*)d_in[14];
  const float* def3_w  = (const float*)d_in[15];
  const float* off5_w  = (const float*)d_in[16];
  const float* off5_b  = (const float*)d_in[17];
  const float* def5_w  = (const float*)d_in[18];
  const float* conv1_w = (const float*)d_in[19];
  const float* conv1_b = (const float*)d_in[20];
  const float* bn3_g   = (const float*)d_in[21];
  const float* bn3_b   = (const float*)d_in[22];
  const float* bn3_m   = (const float*)d_in[23];
  const float* bn3_v   = (const float*)d_in[24];
  const float* conv_w  = (const float*)d_in[25];
  const float* conv_b  = (const float*)d_in[26];
  const float* bn2_g   = (const float*)d_in[27];
  const float* bn2_b   = (const float*)d_in[28];
  const float* bn2_m   = (const float*)d_in[29];
  const float* bn2_v   = (const float*)d_in[30];

  float* ws = (float*)d_ws;
  float* out_b  = ws; ws += 64 * 64 * HW;   // down-proj output frames
  float* U      = ws; ws += 8 * 192 * HW;
  float* t_out  = ws; ws += 8 * 64 * HW;
  float* off3b  = ws; ws += 56 * 18 * HW;
  float* off5b  = ws; ws += 56 * 50 * HW;
  float* dsum   = ws; ws += 56 * 64 * HW;
  float* gmean  = ws; ws += 64 * 64;
  float* multb  = ws; ws += 64 * 256;
  float* wdownT = ws; ws += 256 * 64;
  float* bias1  = ws; ws += 64;
  float* wtT    = ws; ws += 192 * 9 * 64;
  float* AtBt   = ws; ws += 128;
  float* off3T  = ws; ws += 64 * 9 * 18;
  float* off5T  = ws; ws += 64 * 25 * 50;
  float* def3T  = ws; ws += 9 * 64 * 64;
  float* def5T  = ws; ws += 25 * 64 * 64;
  float* c1T    = ws; ws += 64 * 64;
  float* B3     = ws; ws += 64;
  float* gwT    = ws; ws += 64 * 256;
  float* Bg     = ws; ws += 256;

  k_prep<<<64, 256, 0, stream>>>(
      w_down, b_down, bn1_g, bn1_b, bn1_m, bn1_v,
      tconv_w, tconv_b, bnt_g, bnt_b, bnt_m, bnt_v,
      off3_w, def3_w, off5_w, def5_w,
      conv1_w, conv1_b, bn3_g, bn3_b, bn3_m, bn3_v,
      conv_w, conv_b, bn2_g, bn2_b, bn2_m, bn2_v,
      wdownT, bias1, wtT, AtBt, off3T, off5T, def3T, def5T,
      c1T, B3, gwT, Bg);

  k_down<<<dim3(64, 4), 256, 0, stream>>>(x, wdownT, bias1, out_b);
  k_makeU<<<1568, 256, 0, stream>>>(out_b, U);
  k_tconv<<<dim3(8, 4, 8), 256, 0, stream>>>(U, wtT, AtBt, t_out);
  k_offconv<3, 1, 18, 16><<<dim3(56, 4), 256, 0, stream>>>(out_b, off3T, off3_b, off3b);
  k_offconv<5, 2, 50, 8><<<dim3(56, 4), 256, 0, stream>>>(out_b, off5T, off5_b, off5b);
  k_deform<3, 1, false><<<dim3(56, 4), 256, 0, stream>>>(out_b, off3b, def3T, dsum);
  k_deform<5, 2, true><<<dim3(56, 4), 256, 0, stream>>>(out_b, off5b, def5T, dsum);
  k_davg_diff<<<dim3(56, 4), 256, 0, stream>>>(out_b, c1T, B3, dsum);
  k_gmean<<<dim3(64, 64), 64, 0, stream>>>(dsum, t_out, gmean);
  k_gate<<<64, 256, 0, stream>>>(gmean, gwT, Bg, multb);
  k_apply<<<12544, 256, 0, stream>>>(x, multb, (float*)d_out);
}